// Round 7
// baseline (192.507 us; speedup 1.0000x reference)
//
#include <hip/hip_runtime.h>
#include <hip/hip_bf16.h>

// y = (spikes @ V) @ U^T
// spikes: [4096, 16384] f32, V: [16384, 32] f32, U: [16384, 32] f32
// y: [4096, 16384] f32 (268 MB). Mask inputs are dead in the reference.
//
// Phase A (z = spikes@V) via bf16 MFMA 16x16x32, K-split NC ways, depth-2
// named-slot pipeline (r5 structure). NEW in r7: non-temporal cache policy —
// spikes loads and y stores bypass L3 allocation. Theory: spikes(268MB) and
// y(268MB) thrash the 256MB Infinity Cache; dirty y lines evicted by spikes
// reads added ~250MB of hidden writeback under zpart, capping reads ~2.2TB/s.

#define B_DIM 4096
#define NPRE  16384
#define NPOST 16384
#define RDIM  32

#define NC     16                      // K-split chunks
#define CHUNK  (NPRE / NC)             // 1024
#define KSTEPS (CHUNK / 32)            // 32 mfma k-steps per wave

typedef __attribute__((ext_vector_type(8))) short short8;   // 8 bf16 = 4 VGPRs
typedef __attribute__((ext_vector_type(4))) float f32x4;

static __device__ __forceinline__ unsigned pack_bf2(float lo, float hi) {
    union { __hip_bfloat162 h; unsigned u; } c;
    c.h = __float22bfloat162_rn(make_float2(lo, hi));   // v_cvt_pk_bf16_f32
    return c.u;
}

static __device__ __forceinline__ f32x4 nt_load4(const float* p) {
    return __builtin_nontemporal_load(reinterpret_cast<const f32x4*>(p));
}

// ---- V packing: vpack[((kt*2+half)*64 + lane)*8 + e] = bf16(V[kt*32+(lane>>4)*8+e][half*16+(lane&15)])
__global__ void vpack_kernel(const float* __restrict__ V, short* __restrict__ vpack)
{
    const int tid  = blockIdx.x * 256 + threadIdx.x;   // 65536 = 512 kt * 2 half * 64 lane
    const int lane = tid & 63;
    const int half = (tid >> 6) & 1;
    const int kt   = tid >> 7;
    const int n    = half * 16 + (lane & 15);
    const int k0   = kt * 32 + (lane >> 4) * 8;
    union { short8 s; short el[8]; } f;
    #pragma unroll
    for (int e = 0; e < 8; ++e) {
        union { __hip_bfloat16 h; short s; } c;
        c.h = __float2bfloat16(V[(size_t)(k0 + e) * RDIM + n]);
        f.el[e] = c.s;
    }
    *reinterpret_cast<short8*>(vpack + (size_t)tid * 8) = f.s;
}

// ---- phase A: one wave = one (16-row strip, 1024-k chunk) partial ----------
__global__ __launch_bounds__(256) void zpart_kernel(
    const float* __restrict__ spikes, const short* __restrict__ vpack,
    float* __restrict__ part)
{
    const int lane   = threadIdx.x & 63;
    const int widx   = threadIdx.x >> 6;
    const int bstrip = blockIdx.x >> 2;                 // 0..255
    const int kc     = ((blockIdx.x & 3) << 2) | widx;  // 0..15

    const int m  = lane & 15;     // A row within strip  (A: m = lane&15)
    const int kg = lane >> 4;     // k-group, 8 k each   (A: k = kg*8 + e)

    const float* arow  = spikes + (size_t)(bstrip * 16 + m) * NPRE
                                + (size_t)kc * CHUNK + kg * 8;
    const short* bbase = vpack + (size_t)(kc * KSTEPS) * 1024 + lane * 8;

    f32x4 acc0 = {0.f, 0.f, 0.f, 0.f};
    f32x4 acc1 = {0.f, 0.f, 0.f, 0.f};

    // prologue: slots for steps 0 and 1 (spikes: non-temporal, dense 32B/lane)
    f32x4  al0 = nt_load4(arow);
    f32x4  ah0 = nt_load4(arow + 4);
    short8 b00 = *reinterpret_cast<const short8*>(bbase);
    short8 b01 = *reinterpret_cast<const short8*>(bbase + 512);
    f32x4  al1 = nt_load4(arow + 32);
    f32x4  ah1 = nt_load4(arow + 36);
    short8 b10 = *reinterpret_cast<const short8*>(bbase + 1024);
    short8 b11 = *reinterpret_cast<const short8*>(bbase + 1536);

    #pragma unroll 1
    for (int kt = 0; kt < KSTEPS - 2; kt += 2) {
        // step kt: consume slot0, refill with kt+2
        {
            union { short8 s; unsigned u[4]; } af;
            af.u[0] = pack_bf2(al0.x, al0.y);
            af.u[1] = pack_bf2(al0.z, al0.w);
            af.u[2] = pack_bf2(ah0.x, ah0.y);
            af.u[3] = pack_bf2(ah0.z, ah0.w);
            acc0 = __builtin_amdgcn_mfma_f32_16x16x32_bf16(af.s, b00, acc0, 0, 0, 0);
            acc1 = __builtin_amdgcn_mfma_f32_16x16x32_bf16(af.s, b01, acc1, 0, 0, 0);
        }
        al0 = nt_load4(arow + (kt + 2) * 32);
        ah0 = nt_load4(arow + (kt + 2) * 32 + 4);
        b00 = *reinterpret_cast<const short8*>(bbase + (size_t)(kt + 2) * 1024);
        b01 = *reinterpret_cast<const short8*>(bbase + (size_t)(kt + 2) * 1024 + 512);

        // step kt+1: consume slot1, refill with kt+3
        {
            union { short8 s; unsigned u[4]; } af;
            af.u[0] = pack_bf2(al1.x, al1.y);
            af.u[1] = pack_bf2(al1.z, al1.w);
            af.u[2] = pack_bf2(ah1.x, ah1.y);
            af.u[3] = pack_bf2(ah1.z, ah1.w);
            acc0 = __builtin_amdgcn_mfma_f32_16x16x32_bf16(af.s, b10, acc0, 0, 0, 0);
            acc1 = __builtin_amdgcn_mfma_f32_16x16x32_bf16(af.s, b11, acc1, 0, 0, 0);
        }
        al1 = nt_load4(arow + (kt + 3) * 32);
        ah1 = nt_load4(arow + (kt + 3) * 32 + 4);
        b10 = *reinterpret_cast<const short8*>(bbase + (size_t)(kt + 3) * 1024);
        b11 = *reinterpret_cast<const short8*>(bbase + (size_t)(kt + 3) * 1024 + 1536 - 1024);
    }

    // epilogue: steps KSTEPS-2, KSTEPS-1 (no further loads)
    {
        union { short8 s; unsigned u[4]; } af;
        af.u[0] = pack_bf2(al0.x, al0.y);
        af.u[1] = pack_bf2(al0.z, al0.w);
        af.u[2] = pack_bf2(ah0.x, ah0.y);
        af.u[3] = pack_bf2(ah0.z, ah0.w);
        acc0 = __builtin_amdgcn_mfma_f32_16x16x32_bf16(af.s, b00, acc0, 0, 0, 0);
        acc1 = __builtin_amdgcn_mfma_f32_16x16x32_bf16(af.s, b01, acc1, 0, 0, 0);
    }
    {
        union { short8 s; unsigned u[4]; } af;
        af.u[0] = pack_bf2(al1.x, al1.y);
        af.u[1] = pack_bf2(al1.z, al1.w);
        af.u[2] = pack_bf2(ah1.x, ah1.y);
        af.u[3] = pack_bf2(ah1.z, ah1.w);
        acc0 = __builtin_amdgcn_mfma_f32_16x16x32_bf16(af.s, b10, acc0, 0, 0, 0);
        acc1 = __builtin_amdgcn_mfma_f32_16x16x32_bf16(af.s, b11, acc1, 0, 0, 0);
    }

    // C layout: n = lane&15, m = (lane>>4)*4 + j   -> part[kc][bstrip*16+m][r]
    float* pout = part + ((size_t)kc * B_DIM + bstrip * 16) * RDIM;
    #pragma unroll
    for (int j = 0; j < 4; ++j) {
        const int row = kg * 4 + j;
        pout[row * RDIM + (lane & 15)]      = acc0[j];
        pout[row * RDIM + 16 + (lane & 15)] = acc1[j];
    }
}

// ---- z reduction: z[b][r] = sum_c part[c][b][r] ---------------------------
__global__ void zreduce_kernel(const float* __restrict__ part, float* __restrict__ z)
{
    const int idx = (blockIdx.x * blockDim.x + threadIdx.x) * 4;  // 131072 floats
    float sx = 0.f, sy = 0.f, sz = 0.f, sw = 0.f;
    #pragma unroll
    for (int c = 0; c < NC; ++c) {
        const float4 p = *reinterpret_cast<const float4*>(
            &part[(size_t)c * (B_DIM * RDIM) + idx]);
        sx += p.x; sy += p.y; sz += p.z; sw += p.w;
    }
    float4 s4; s4.x = sx; s4.y = sy; s4.z = sz; s4.w = sw;
    *reinterpret_cast<float4*>(&z[idx]) = s4;
}

// ---- phase B: y[b][j] = sum_r z[b][r] * U[j][r] ---------------------------
#define TJ 256
#define TB 64

__global__ __launch_bounds__(256) void ykernel(
    const float* __restrict__ z, const float* __restrict__ U,
    float* __restrict__ y)
{
    const int j  = blockIdx.x * TJ + threadIdx.x;
    const int b0 = blockIdx.y * TB;

    float u[RDIM];
    #pragma unroll
    for (int q = 0; q < 8; ++q) {
        const float4 v = *reinterpret_cast<const float4*>(&U[(size_t)j * RDIM + q * 4]);
        u[q * 4 + 0] = v.x; u[q * 4 + 1] = v.y; u[q * 4 + 2] = v.z; u[q * 4 + 3] = v.w;
    }

    for (int bb = 0; bb < TB; ++bb) {
        const float* zr = &z[(size_t)(b0 + bb) * RDIM];
        float a0 = 0.f, a1 = 0.f, a2 = 0.f, a3 = 0.f;
        #pragma unroll
        for (int r = 0; r < RDIM; r += 4) {
            a0 += zr[r + 0] * u[r + 0];
            a1 += zr[r + 1] * u[r + 1];
            a2 += zr[r + 2] * u[r + 2];
            a3 += zr[r + 3] * u[r + 3];
        }
        // non-temporal: y is write-once streaming; keep it out of L3 so spikes
        // reads don't evict dirty y lines next replay
        __builtin_nontemporal_store((a0 + a1) + (a2 + a3),
                                    &y[(size_t)(b0 + bb) * NPOST + j]);
    }
}

extern "C" void kernel_launch(void* const* d_in, const int* in_sizes, int n_in,
                              void* d_out, int out_size, void* d_ws, size_t ws_size,
                              hipStream_t stream)
{
    const float* spikes = (const float*)d_in[0];   // [4096, 16384]
    const float* U      = (const float*)d_in[1];   // [16384, 32]
    const float* V      = (const float*)d_in[2];   // [16384, 32]

    float* y     = (float*)d_out;
    float* part  = (float*)d_out;                         // [16][4096][32] f32 = 8 MB
    short* vpack = (short*)((float*)d_out + (size_t)NC * B_DIM * RDIM);  // 1 MB after partials
    float* z     = (float*)d_ws;                          // 512 KB

    vpack_kernel<<<256, 256, 0, stream>>>(V, vpack);
    zpart_kernel<<<dim3(1024), 256, 0, stream>>>(spikes, vpack, part);
    zreduce_kernel<<<dim3((B_DIM * RDIM / 4) / 256), 256, 0, stream>>>(part, z);
    ykernel<<<dim3(NPOST / TJ, B_DIM / TB), 256, 0, stream>>>(z, U, y);
}

// Round 8
// 174.873 us; speedup vs baseline: 1.1008x; 1.1008x over previous
//
#include <hip/hip_runtime.h>
#include <hip/hip_bf16.h>

// y = (spikes @ V) @ U^T
// spikes: [4096, 16384] f32, V: [16384, 32] f32, U: [16384, 32] f32
// y: [4096, 16384] f32 (268 MB). Mask inputs are dead in the reference.
//
// r8 theory: rounds 4-7 all read spikes at ~2.2 TB/s because every structure
// touched each row in 128-256B pieces with thousands of interleaved streams ->
// ~1 DRAM page activation per touch. Fix: each global_load_lds reads 1 KB
// CONTIGUOUS from ONE row (64 lanes x 16B), rows advance sequentially across
// tiles -> long page-hit streaks. LDS row stride 1040 B (pad 16) spreads the
// MFMA fragment reads uniformly over bank slots; padding is legal because DMA
// linearity is only needed within one instruction.

#define B_DIM 4096
#define NPRE  16384
#define NPOST 16384
#define RDIM  32

#define NC      16               // k-chunks
#define CHUNK   1024             // k per block (NPRE/NC)
#define NCP     64               // partials = NC * 4 waves
#define TILEK   256              // k per LDS tile (1 KB per row)
#define NTILE   4                // CHUNK/TILEK
#define ROWSTRB 1040             // LDS bytes per row (1024 + 16 pad)
#define TILEB   (16 * ROWSTRB)   // 16640 B per buffer

typedef __attribute__((ext_vector_type(8))) short short8;   // 8 bf16
typedef __attribute__((ext_vector_type(4))) float f32x4;
typedef const __attribute__((address_space(1))) void GAS;
typedef __attribute__((address_space(3))) void LAS;

static __device__ __forceinline__ unsigned pack_bf2(float lo, float hi) {
    union { __hip_bfloat162 h; unsigned u; } c;
    c.h = __float22bfloat162_rn(make_float2(lo, hi));   // v_cvt_pk_bf16_f32
    return c.u;
}

// ---- V packing (proven r4): vpack[((kt*2+half)*64 + lane)*8 + e]
//      = bf16(V[kt*32 + (lane>>4)*8 + e][half*16 + (lane&15)])
__global__ void vpack_kernel(const float* __restrict__ V, short* __restrict__ vpack)
{
    const int tid  = blockIdx.x * 256 + threadIdx.x;   // 65536
    const int lane = tid & 63;
    const int half = (tid >> 6) & 1;
    const int kt   = tid >> 7;
    const int n    = half * 16 + (lane & 15);
    const int k0   = kt * 32 + (lane >> 4) * 8;
    union { short8 s; short el[8]; } f;
    #pragma unroll
    for (int e = 0; e < 8; ++e) {
        union { __hip_bfloat16 h; short s; } c;
        c.h = __float2bfloat16(V[(size_t)(k0 + e) * RDIM + n]);
        f.el[e] = c.s;
    }
    *reinterpret_cast<short8*>(vpack + (size_t)tid * 8) = f.s;
}

// ---- phase A: block = (16-row strip, 1024-k chunk); wave w computes tile
// k-steps {2w, 2w+1} -> partial index kc*4+w. DMA: 1 KB per instr per row.
__global__ __launch_bounds__(256) void zpart_kernel(
    const float* __restrict__ spikes, const short* __restrict__ vpack,
    float* __restrict__ part)
{
    __shared__ char smem[2 * TILEB];   // 33,280 B -> 4 blocks/CU

    const int tid   = threadIdx.x;
    const int lane  = tid & 63;
    const int w     = tid >> 6;        // wave 0..3
    const int strip = blockIdx.x;      // 0..255
    const int kc    = blockIdx.y;      // 0..15
    const int brow  = strip * 16;

    const int m  = lane & 15;          // fragment row
    const int kg = lane >> 4;          // k-group

    // DMA sources: wave w stages rows w*4..w*4+3; each instr = 1 KB of one row
    const float* g[4];
    #pragma unroll
    for (int q = 0; q < 4; ++q)
        g[q] = spikes + (size_t)(brow + w * 4 + q) * NPRE
                      + (size_t)kc * CHUNK + lane * 4;

    // B fragments: wave w consumes global k-steps kc*32 + t*8 + {2w, 2w+1}
    const short* bb = vpack + ((size_t)(kc * 32 + 2 * w)) * 1024 + lane * 8;

    f32x4 acc0 = {0.f, 0.f, 0.f, 0.f};
    f32x4 acc1 = {0.f, 0.f, 0.f, 0.f};

    // prologue: tile 0 -> buf 0
    #pragma unroll
    for (int q = 0; q < 4; ++q)
        __builtin_amdgcn_global_load_lds((GAS*)g[q],
            (LAS*)(smem + (w * 4 + q) * ROWSTRB), 16, 0, 0);

    #pragma unroll
    for (int t = 0; t < NTILE; ++t) {
        __syncthreads();               // vmcnt drain: tile t resident in buf t&1

        if (t + 1 < NTILE) {           // DMA tile t+1 -> other buf, flies under wait
            char* nb = smem + ((t + 1) & 1) * TILEB;
            #pragma unroll
            for (int q = 0; q < 4; ++q)
                __builtin_amdgcn_global_load_lds((GAS*)(g[q] + (size_t)(t + 1) * TILEK),
                    (LAS*)(nb + (w * 4 + q) * ROWSTRB), 16, 0, 0);
        }

        const char*  sb = smem + (t & 1) * TILEB + m * ROWSTRB;
        const short* bt = bb + (size_t)t * 8192;       // t*8 k-steps * 1024
        const short8 b00 = *reinterpret_cast<const short8*>(bt);
        const short8 b01 = *reinterpret_cast<const short8*>(bt + 512);
        const short8 b10 = *reinterpret_cast<const short8*>(bt + 1024);
        const short8 b11 = *reinterpret_cast<const short8*>(bt + 1536);

        {   // tile-local k-step 2w
            const int ks = 2 * w;
            const f32x4 al = *reinterpret_cast<const f32x4*>(sb + ks * 128 + kg * 32);
            const f32x4 ah = *reinterpret_cast<const f32x4*>(sb + ks * 128 + kg * 32 + 16);
            union { short8 s; unsigned u[4]; } af;
            af.u[0] = pack_bf2(al.x, al.y);
            af.u[1] = pack_bf2(al.z, al.w);
            af.u[2] = pack_bf2(ah.x, ah.y);
            af.u[3] = pack_bf2(ah.z, ah.w);
            acc0 = __builtin_amdgcn_mfma_f32_16x16x32_bf16(af.s, b00, acc0, 0, 0, 0);
            acc1 = __builtin_amdgcn_mfma_f32_16x16x32_bf16(af.s, b01, acc1, 0, 0, 0);
        }
        {   // tile-local k-step 2w+1
            const int ks = 2 * w + 1;
            const f32x4 al = *reinterpret_cast<const f32x4*>(sb + ks * 128 + kg * 32);
            const f32x4 ah = *reinterpret_cast<const f32x4*>(sb + ks * 128 + kg * 32 + 16);
            union { short8 s; unsigned u[4]; } af;
            af.u[0] = pack_bf2(al.x, al.y);
            af.u[1] = pack_bf2(al.z, al.w);
            af.u[2] = pack_bf2(ah.x, ah.y);
            af.u[3] = pack_bf2(ah.z, ah.w);
            acc0 = __builtin_amdgcn_mfma_f32_16x16x32_bf16(af.s, b10, acc0, 0, 0, 0);
            acc1 = __builtin_amdgcn_mfma_f32_16x16x32_bf16(af.s, b11, acc1, 0, 0, 0);
        }
    }

    // C layout: n = lane&15, out-row = kg*4 + j  -> part[kc*4+w][brow + row][r]
    float* pout = part + ((size_t)(kc * 4 + w) * B_DIM + brow) * RDIM;
    #pragma unroll
    for (int j = 0; j < 4; ++j) {
        const int ro = (kg * 4 + j) * RDIM;
        pout[ro + m]      = acc0[j];
        pout[ro + 16 + m] = acc1[j];
    }
}

// ---- z reduction: z[b][r] = sum_c part[c][b][r], c = 0..63 ----------------
__global__ void zreduce_kernel(const float* __restrict__ part, float* __restrict__ z)
{
    const int idx = (blockIdx.x * blockDim.x + threadIdx.x) * 4;  // 131072 floats
    float sx = 0.f, sy = 0.f, sz = 0.f, sw = 0.f;
    #pragma unroll 8
    for (int c = 0; c < NCP; ++c) {
        const float4 p = *reinterpret_cast<const float4*>(
            &part[(size_t)c * (B_DIM * RDIM) + idx]);
        sx += p.x; sy += p.y; sz += p.z; sw += p.w;
    }
    float4 s4; s4.x = sx; s4.y = sy; s4.z = sz; s4.w = sw;
    *reinterpret_cast<float4*>(&z[idx]) = s4;
}

// ---- phase B: y[b][j] = sum_r z[b][r] * U[j][r] ---------------------------
#define TJ 256
#define TB 64

__global__ __launch_bounds__(256) void ykernel(
    const float* __restrict__ z, const float* __restrict__ U,
    float* __restrict__ y)
{
    const int j  = blockIdx.x * TJ + threadIdx.x;
    const int b0 = blockIdx.y * TB;

    float u[RDIM];
    #pragma unroll
    for (int q = 0; q < 8; ++q) {
        const float4 v = *reinterpret_cast<const float4*>(&U[(size_t)j * RDIM + q * 4]);
        u[q * 4 + 0] = v.x; u[q * 4 + 1] = v.y; u[q * 4 + 2] = v.z; u[q * 4 + 3] = v.w;
    }

    for (int bb = 0; bb < TB; ++bb) {
        const float* zr = &z[(size_t)(b0 + bb) * RDIM];
        float a0 = 0.f, a1 = 0.f, a2 = 0.f, a3 = 0.f;
        #pragma unroll
        for (int r = 0; r < RDIM; r += 4) {
            a0 += zr[r + 0] * u[r + 0];
            a1 += zr[r + 1] * u[r + 1];
            a2 += zr[r + 2] * u[r + 2];
            a3 += zr[r + 3] * u[r + 3];
        }
        y[(size_t)(b0 + bb) * NPOST + j] = (a0 + a1) + (a2 + a3);
    }
}

extern "C" void kernel_launch(void* const* d_in, const int* in_sizes, int n_in,
                              void* d_out, int out_size, void* d_ws, size_t ws_size,
                              hipStream_t stream)
{
    const float* spikes = (const float*)d_in[0];   // [4096, 16384]
    const float* U      = (const float*)d_in[1];   // [16384, 32]
    const float* V      = (const float*)d_in[2];   // [16384, 32]

    float* y     = (float*)d_out;
    float* part  = (float*)d_out;                         // [64][4096][32] f32 = 32 MB
    short* vpack = (short*)((float*)d_out + (size_t)NCP * B_DIM * RDIM);  // 1 MB after partials
    float* z     = (float*)d_ws;                          // 512 KB

    vpack_kernel<<<256, 256, 0, stream>>>(V, vpack);
    zpart_kernel<<<dim3(B_DIM / 16, NC), 256, 0, stream>>>(spikes, vpack, part);
    zreduce_kernel<<<dim3((B_DIM * RDIM / 4) / 256), 256, 0, stream>>>(part, z);
    ykernel<<<dim3(NPOST / TJ, B_DIM / TB), 256, 0, stream>>>(z, U, y);
}

// Round 9
// 163.306 us; speedup vs baseline: 1.1788x; 1.0708x over previous
//
#include <hip/hip_runtime.h>
#include <hip/hip_bf16.h>

// y = (spikes @ V) @ U^T
// spikes: [4096, 16384] f32, V: [16384, 32] f32, U: [16384, 32] f32
// y: [4096, 16384] f32 (268 MB). Mask inputs are dead in the reference.
//
// r9 theory: spikes reads cap at ~2.2 TB/s in all prior rounds because
// 16K-32K concurrent row-streams thrash DRAM page activations. This version
// uses 256 blocks x (16 rows x full K): ~4K strictly-sequential streams, each
// advancing in 2 KB bursts, 32 KB tile prefetch in flight per CU. Cross-wave
// z-reduction done in-kernel (part/zreduce kernels eliminated).

#define B_DIM 4096
#define NPRE  16384
#define NPOST 16384
#define RDIM  32

#define ROWS   16
#define TILEK  512                    // k per tile (2 KB per row)
#define NTILE  (NPRE / TILEK)         // 32
#define ROWB   2064                   // LDS bytes per row (2048 + 16 pad -> 2-way-free banks)
#define TBUF   (ROWS * ROWB)          // 33024 B per buffer

typedef __attribute__((ext_vector_type(8))) short short8;   // 8 bf16
typedef __attribute__((ext_vector_type(4))) float f32x4;
typedef const __attribute__((address_space(1))) void GAS;
typedef __attribute__((address_space(3))) void LAS;

static __device__ __forceinline__ unsigned pack_bf2(float lo, float hi) {
    union { __hip_bfloat162 h; unsigned u; } c;
    c.h = __float22bfloat162_rn(make_float2(lo, hi));   // v_cvt_pk_bf16_f32
    return c.u;
}

// ---- V packing (proven r4): vpack[((kt*2+half)*64 + lane)*8 + e]
//      = bf16(V[kt*32 + (lane>>4)*8 + e][half*16 + (lane&15)])
__global__ void vpack_kernel(const float* __restrict__ V, short* __restrict__ vpack)
{
    const int tid  = blockIdx.x * 256 + threadIdx.x;   // 65536
    const int lane = tid & 63;
    const int half = (tid >> 6) & 1;
    const int kt   = tid >> 7;
    const int n    = half * 16 + (lane & 15);
    const int k0   = kt * 32 + (lane >> 4) * 8;
    union { short8 s; short el[8]; } f;
    #pragma unroll
    for (int e = 0; e < 8; ++e) {
        union { __hip_bfloat16 h; short s; } c;
        c.h = __float2bfloat16(V[(size_t)(k0 + e) * RDIM + n]);
        f.el[e] = c.s;
    }
    *reinterpret_cast<short8*>(vpack + (size_t)tid * 8) = f.s;
}

// ---- phase A: block = 16 rows x full K. Wave w streams rows 2w,2w+1
// linearly via DMA; waves split each tile's 16 k-steps as {2w, 2w+1}.
__global__ __launch_bounds__(512) void zpart_kernel(
    const float* __restrict__ spikes, const short* __restrict__ vpack,
    float* __restrict__ z)
{
    __shared__ char smem[2 * TBUF];    // 66 KB

    const int tid  = threadIdx.x;
    const int lane = tid & 63;
    const int w    = tid >> 6;         // wave 0..7
    const int brow = blockIdx.x * ROWS;

    const int m  = lane & 15;          // fragment batch-row
    const int kg = lane >> 4;          // k-group

    // DMA descriptors: instr q covers row 2w+(q>>1), KB half kp=q&1
    const float* g[4];
    int ldst[4];
    #pragma unroll
    for (int q = 0; q < 4; ++q) {
        const int row = 2 * w + (q >> 1);
        const int kp  = q & 1;
        g[q]   = spikes + (size_t)(brow + row) * NPRE + kp * 256 + lane * 4;
        ldst[q] = row * ROWB + kp * 1024;
    }

    f32x4 acc0 = {0.f, 0.f, 0.f, 0.f};
    f32x4 acc1 = {0.f, 0.f, 0.f, 0.f};

    // prologue: tile 0 -> buf 0
    #pragma unroll
    for (int q = 0; q < 4; ++q)
        __builtin_amdgcn_global_load_lds((GAS*)g[q], (LAS*)(smem + ldst[q]), 16, 0, 0);

    #pragma unroll 1
    for (int t = 0; t < NTILE; ++t) {
        __syncthreads();               // drains vmcnt: tile t resident in buf t&1

        if (t + 1 < NTILE) {           // prefetch whole next tile (32 KB in flight)
            char* nb = smem + ((t + 1) & 1) * TBUF;
            #pragma unroll
            for (int q = 0; q < 4; ++q)
                __builtin_amdgcn_global_load_lds(
                    (GAS*)(g[q] + (size_t)(t + 1) * TILEK),
                    (LAS*)(nb + ldst[q]), 16, 0, 0);
        }

        const char* sb = smem + (t & 1) * TBUF + m * ROWB;
        #pragma unroll
        for (int p = 0; p < 2; ++p) {
            const int ks = 2 * w + p;                  // tile-local k-step
            const int kt = t * 16 + ks;                // global k-step
            const short* bt = vpack + (size_t)kt * 1024 + lane * 8;
            const short8 b0 = *reinterpret_cast<const short8*>(bt);
            const short8 b1 = *reinterpret_cast<const short8*>(bt + 512);
            const f32x4 al = *reinterpret_cast<const f32x4*>(sb + ks * 128 + kg * 32);
            const f32x4 ah = *reinterpret_cast<const f32x4*>(sb + ks * 128 + kg * 32 + 16);
            union { short8 s; unsigned u[4]; } af;
            af.u[0] = pack_bf2(al.x, al.y);
            af.u[1] = pack_bf2(al.z, al.w);
            af.u[2] = pack_bf2(ah.x, ah.y);
            af.u[3] = pack_bf2(ah.z, ah.w);
            acc0 = __builtin_amdgcn_mfma_f32_16x16x32_bf16(af.s, b0, acc0, 0, 0, 0);
            acc1 = __builtin_amdgcn_mfma_f32_16x16x32_bf16(af.s, b1, acc1, 0, 0, 0);
        }
    }

    // ---- in-kernel cross-wave reduction: 8 partials -> z[16][32] ----------
    __syncthreads();                   // all tile reads done; reuse smem
    float* red = reinterpret_cast<float*>(smem);   // [8][16][32] = 16 KB
    {
        // C layout: batch-row = kg*4 + j, r = lane&15 (acc0) / 16+(lane&15) (acc1)
        float* rw = red + w * (ROWS * RDIM);
        #pragma unroll
        for (int j = 0; j < 4; ++j) {
            rw[(kg * 4 + j) * RDIM + m]      = acc0[j];
            rw[(kg * 4 + j) * RDIM + 16 + m] = acc1[j];
        }
    }
    __syncthreads();
    {
        const int e = tid;             // 512 = 16 rows x 32 r exactly
        float s = 0.f;
        #pragma unroll
        for (int ww = 0; ww < 8; ++ww) s += red[ww * (ROWS * RDIM) + e];
        z[(size_t)(brow + (e >> 5)) * RDIM + (e & 31)] = s;
    }
}

// ---- phase B: y[b][j] = sum_r z[b][r] * U[j][r] ---------------------------
#define TJ 256
#define TB 64

__global__ __launch_bounds__(256) void ykernel(
    const float* __restrict__ z, const float* __restrict__ U,
    float* __restrict__ y)
{
    const int j  = blockIdx.x * TJ + threadIdx.x;
    const int b0 = blockIdx.y * TB;

    float u[RDIM];
    #pragma unroll
    for (int q = 0; q < 8; ++q) {
        const float4 v = *reinterpret_cast<const float4*>(&U[(size_t)j * RDIM + q * 4]);
        u[q * 4 + 0] = v.x; u[q * 4 + 1] = v.y; u[q * 4 + 2] = v.z; u[q * 4 + 3] = v.w;
    }

    for (int bb = 0; bb < TB; ++bb) {
        const float* zr = &z[(size_t)(b0 + bb) * RDIM];
        float a0 = 0.f, a1 = 0.f, a2 = 0.f, a3 = 0.f;
        #pragma unroll
        for (int r = 0; r < RDIM; r += 4) {
            a0 += zr[r + 0] * u[r + 0];
            a1 += zr[r + 1] * u[r + 1];
            a2 += zr[r + 2] * u[r + 2];
            a3 += zr[r + 3] * u[r + 3];
        }
        y[(size_t)(b0 + bb) * NPOST + j] = (a0 + a1) + (a2 + a3);
    }
}

extern "C" void kernel_launch(void* const* d_in, const int* in_sizes, int n_in,
                              void* d_out, int out_size, void* d_ws, size_t ws_size,
                              hipStream_t stream)
{
    const float* spikes = (const float*)d_in[0];   // [4096, 16384]
    const float* U      = (const float*)d_in[1];   // [16384, 32]
    const float* V      = (const float*)d_in[2];   // [16384, 32]

    float* y     = (float*)d_out;
    short* vpack = (short*)d_out;      // 1 MB at front of d_out; consumed by zpart
                                       // before ykernel overwrites with y
    float* z     = (float*)d_ws;       // 512 KB

    vpack_kernel<<<256, 256, 0, stream>>>(V, vpack);
    zpart_kernel<<<B_DIM / ROWS, 512, 0, stream>>>(spikes, vpack, z);
    ykernel<<<dim3(NPOST / TJ, B_DIM / TB), 256, 0, stream>>>(z, U, y);
}